// Round 5
// baseline (380.651 us; speedup 1.0000x reference)
//
#include <hip/hip_runtime.h>
#include <cstdint>
#include <cstddef>

// GLA layer: B=4, T=4096, D=1024, H=16, S=64
// fp16 pipeline, packed weights (a rows | interleaved bg/v rows).
// GEMM = 32x32x16 MFMA, 128x128 tile, BK=64, global_load_lds staging with
// conflict-free octet swizzle f(row) = (row&7) ^ (((row>>3)&3)<<1).
// GEMM1 epilogue: a = sigmoid(.), bv = sigmoid(.)*v (lane-pair shfl),
// LDS-staged f16x8 coalesced stores. Scan: 128 chunks x 32 steps,
// segment-parallel pass2. GEMM2 -> y fp32 (128B-segment direct stores).

typedef _Float16 f16;
typedef _Float16 f16x2 __attribute__((ext_vector_type(2)));
typedef _Float16 f16x8 __attribute__((ext_vector_type(8)));
typedef float    f32x16 __attribute__((ext_vector_type(16)));

__device__ __forceinline__ void gload_lds16(const void* g, void* l) {
  __builtin_amdgcn_global_load_lds(
      (const __attribute__((address_space(1))) void*)g,
      (__attribute__((address_space(3))) void*)l, 16, 0, 0);
}

__device__ __forceinline__ float sigmoidf_(float x) {
  return 1.0f / (1.0f + __expf(-x));
}

// ---------------- fused cast+pack fp32 -> fp16 ----------------
__global__ __launch_bounds__(256) void cast_pack(
    const float* __restrict__ x, const float* __restrict__ gw,
    const float* __restrict__ vw, const float* __restrict__ ow,
    f16* __restrict__ xh, f16* __restrict__ wgv, f16* __restrict__ owb) {
  const int XG = 2097152, GG = 262144, VG = 131072, OG = 131072;
  int id = blockIdx.x * 256 + threadIdx.x;
  const float* src;
  f16* dst;
  if (id < XG) {
    src = x + (size_t)id * 8;
    dst = xh + (size_t)id * 8;
  } else if (id < XG + GG) {
    int g = id - XG;
    int row = g >> 7, col = g & 127;
    int drow = (row < 1024) ? row : (1024 + 2 * (row - 1024));
    src = gw + ((size_t)row << 10) + col * 8;
    dst = wgv + ((size_t)drow << 10) + col * 8;
  } else if (id < XG + GG + VG) {
    int g = id - XG - GG;
    int row = g >> 7, col = g & 127;
    int drow = 1024 + 2 * row + 1;
    src = vw + ((size_t)row << 10) + col * 8;
    dst = wgv + ((size_t)drow << 10) + col * 8;
  } else if (id < XG + GG + VG + OG) {
    int g = id - XG - GG - VG;
    src = ow + (size_t)g * 8;
    dst = owb + (size_t)g * 8;
  } else {
    return;
  }
  float4 v0 = ((const float4*)src)[0], v1 = ((const float4*)src)[1];
  f16x8 o;
  o[0] = (f16)v0.x; o[1] = (f16)v0.y; o[2] = (f16)v0.z; o[3] = (f16)v0.w;
  o[4] = (f16)v1.x; o[5] = (f16)v1.y; o[6] = (f16)v1.z; o[7] = (f16)v1.w;
  *(f16x8*)dst = o;
}

// ------------- fp16 MFMA GEMM (32x32x16): C[N,M] = A[N,K] * B[M,K]^T -------
// 128x128 tile, BK=64, 4 waves (64x64 each = 2x2 of 32x32x16 MFMA).
// Octet swizzle: slot (row, p) holds k-octet p ^ fsw(row),
//   fsw(row) = (row&7) ^ (((row>>3)&3)<<1)  -- conflict-free frag reads.
template <int EPI>
__global__ __launch_bounds__(256, 3) void gemm_bt(
    const f16* __restrict__ A, const f16* __restrict__ Bw,
    const float* __restrict__ gate_b,
    void* __restrict__ o0v, void* __restrict__ o1v) {
  constexpr int K = 1024;
  __shared__ __align__(16) f16 S[17920];  // K-loop 32KB; a-epi 34.8KB
  f16* As = S;
  f16* Bs = S + 8192;
  const int tid  = threadIdx.x;
  const int lane = tid & 63;
  const int half = lane >> 5;        // 0/1: k-octet half for 32x32 frags
  const int l31  = lane & 31;
  const int wv   = tid >> 6;
  const int wrow = wv & 1, wcol = wv >> 1;
  const int n0 = blockIdx.y * 128;
  const int m0 = blockIdx.x * 128;

  const f16* ga[4];
  const f16* gb[4];
  f16* la[4];
  f16* lb[4];
#pragma unroll
  for (int j = 0; j < 4; ++j) {
    int s   = j * 256 + tid;           // 16B slot in [0,1024)
    int row = s >> 3;                  // tile row
    int fsw = (row & 7) ^ (((row >> 3) & 3) << 1);
    int kc  = (s & 7) ^ fsw;           // swizzled k-octet (8 f16)
    ga[j] = A  + (size_t)(n0 + row) * K + kc * 8;
    gb[j] = Bw + (size_t)(m0 + row) * K + kc * 8;
    la[j] = &As[s * 8];
    lb[j] = &Bs[s * 8];
  }

  f32x16 acc[2][2];
#pragma unroll
  for (int mi = 0; mi < 2; ++mi)
#pragma unroll
    for (int ni = 0; ni < 2; ++ni)
#pragma unroll
      for (int e = 0; e < 16; ++e) acc[mi][ni][e] = 0.f;

  const int jsw = (l31 >> 3) << 1;     // frag-read part of fsw from l31 bits 3-4
  for (int k0 = 0; k0 < K; k0 += 64) {
#pragma unroll
    for (int j = 0; j < 4; ++j) gload_lds16(ga[j], la[j]);
#pragma unroll
    for (int j = 0; j < 4; ++j) gload_lds16(gb[j], lb[j]);
#pragma unroll
    for (int j = 0; j < 4; ++j) { ga[j] += 64; gb[j] += 64; }
    __syncthreads();
#pragma unroll
    for (int kk = 0; kk < 4; ++kk) {   // 4 x K=16 steps
      f16x8 af[2], bfv[2];
#pragma unroll
      for (int mi = 0; mi < 2; ++mi) {
        int row  = wrow * 64 + mi * 32 + l31;
        int slot = row * 8 + (((kk << 1) | half) ^ (row & 7) ^ jsw);
        af[mi] = *(const f16x8*)(&As[slot * 8]);
      }
#pragma unroll
      for (int ni = 0; ni < 2; ++ni) {
        int row  = wcol * 64 + ni * 32 + l31;
        int slot = row * 8 + (((kk << 1) | half) ^ (row & 7) ^ jsw);
        bfv[ni] = *(const f16x8*)(&Bs[slot * 8]);
      }
#pragma unroll
      for (int mi = 0; mi < 2; ++mi)
#pragma unroll
        for (int ni = 0; ni < 2; ++ni)
          acc[mi][ni] = __builtin_amdgcn_mfma_f32_32x32x16_f16(
              af[mi], bfv[ni], acc[mi][ni], 0, 0, 0);
    }
    __syncthreads();
  }

  // C/D layout (32x32): col = l31, row = (r&3) + 8*(r>>2) + 4*half
  if (EPI == 1) {
#pragma unroll
    for (int mi = 0; mi < 2; ++mi)
#pragma unroll
      for (int ni = 0; ni < 2; ++ni) {
        const int m = m0 + wcol * 64 + ni * 32 + l31;
#pragma unroll
        for (int r = 0; r < 16; ++r) {
          const int n = n0 + wrow * 64 + mi * 32 + (r & 3) + 8 * (r >> 2) +
                        4 * half;
          ((float*)o0v)[(size_t)n * 1024 + m] = acc[mi][ni][r];
        }
      }
    return;
  }

  if (m0 < 1024) {
    // forget gate a: sigmoid, stage 128x128 f16 (stride 136)
#pragma unroll
    for (int mi = 0; mi < 2; ++mi)
#pragma unroll
      for (int ni = 0; ni < 2; ++ni) {
        const int ml = wcol * 64 + ni * 32 + l31;
        const float bias = gate_b[m0 + ml];
#pragma unroll
        for (int r = 0; r < 16; ++r) {
          const int nl = wrow * 64 + mi * 32 + (r & 3) + 8 * (r >> 2) +
                         4 * half;
          S[nl * 136 + ml] = (f16)sigmoidf_(acc[mi][ni][r] + bias);
        }
      }
    __syncthreads();
    f16* o0 = (f16*)o0v;
#pragma unroll
    for (int i = 0; i < 8; ++i) {
      int ch = i * 256 + tid;
      int row = ch >> 4, cc = ch & 15;
      f16x8 vv = *(const f16x8*)&S[row * 136 + cc * 8];
      *(f16x8*)(o0 + (size_t)(n0 + row) * 1024 + m0 + cc * 8) = vv;
    }
  } else {
    // bv = sigmoid(bg + bias) * v : even col bg, odd col v (same channel)
    const int c0 = (m0 - 1024) >> 1;
#pragma unroll
    for (int mi = 0; mi < 2; ++mi)
#pragma unroll
      for (int ni = 0; ni < 2; ++ni) {
        const int ml = wcol * 64 + ni * 32 + l31;
#pragma unroll
        for (int r = 0; r < 16; ++r) {
          float val = acc[mi][ni][r];
          float pv = __shfl_xor(val, 1, 64);  // partner's value
          if (!(lane & 1)) {
            const int c = ml >> 1;  // local channel 0..63
            const int nl = wrow * 64 + mi * 32 + (r & 3) + 8 * (r >> 2) +
                           4 * half;
            S[nl * 72 + c] =
                (f16)(sigmoidf_(val + gate_b[1024 + c0 + c]) * pv);
          }
        }
      }
    __syncthreads();
    f16* o1 = (f16*)o1v;
#pragma unroll
    for (int i = 0; i < 4; ++i) {
      int ch = i * 256 + tid;
      int row = ch >> 3, cc = ch & 7;
      f16x8 vv = *(const f16x8*)&S[row * 72 + cc * 8];
      *(f16x8*)(o1 + (size_t)(n0 + row) * 1024 + c0 + cc * 8) = vv;
    }
  }
}

// ---------------- chunked scan: h_t = a_t*h_{t-1} + bv_t ----------------
// T=4096 = 128 chunks x 32; 2 channels/thread (f16x2).
__global__ __launch_bounds__(256) void scan_pass1(
    const f16x2* __restrict__ a, const f16x2* __restrict__ bv,
    float2* __restrict__ Ac, float2* __restrict__ Uc) {
  const int c2 = blockIdx.x * 256 + threadIdx.x;  // 0..511
  const int j = blockIdx.y;                       // 0..127
  const int b = blockIdx.z;
  const size_t base = ((size_t)(b * 4096 + j * 32)) * 512 + c2;
  float P0 = 1.f, P1 = 1.f, U0 = 0.f, U1 = 0.f;
#pragma unroll 8
  for (int t = 0; t < 32; ++t) {
    const size_t o = base + (size_t)t * 512;
    f16x2 at = a[o], bt = bv[o];
    float a0 = (float)at[0], a1 = (float)at[1];
    P0 *= a0; P1 *= a1;
    U0 = a0 * U0 + (float)bt[0];
    U1 = a1 * U1 + (float)bt[1];
  }
  const size_t o = ((size_t)(b * 128 + j)) * 512 + c2;
  Ac[o] = make_float2(P0, P1);
  Uc[o] = make_float2(U0, U1);
}

// segment-parallel inter-chunk scan: 64 channels x 4 segments of 32 chunks
__global__ __launch_bounds__(256) void scan_pass2(
    const float* __restrict__ Ac, const float* __restrict__ Uc,
    const float* __restrict__ h_prev, float* __restrict__ Hs,
    float* __restrict__ hlast) {
  __shared__ float SA[4][64], SU[4][64];
  const int tid = threadIdx.x;
  const int seg = tid >> 6;            // 0..3
  const int cl  = tid & 63;
  const int ch  = blockIdx.x * 64 + cl;  // 0..4095
  const int b = ch >> 10, c = ch & 1023;
  float A = 1.f, U = 0.f;
  for (int t = 0; t < 32; ++t) {
    const int j = seg * 32 + t;
    const size_t o = ((size_t)(b * 128 + j)) * 1024 + c;
    float av = Ac[o], uv = Uc[o];
    U = av * U + uv;
    A = av * A;
  }
  SA[seg][cl] = A;
  SU[seg][cl] = U;
  __syncthreads();
  float Ae = 1.f, Ue = 0.f;
  for (int s = 0; s < seg; ++s) {
    float av = SA[s][cl], uv = SU[s][cl];
    Ue = av * Ue + uv;
    Ae = av * Ae;
  }
  float H = Ae * h_prev[b * 1024 + c] + Ue;  // state entering my segment
  for (int t = 0; t < 32; ++t) {
    const int j = seg * 32 + t;
    const size_t o = ((size_t)(b * 128 + j)) * 1024 + c;
    Hs[o] = H;
    H = Ac[o] * H + Uc[o];
  }
  if (seg == 3) hlast[b * 1024 + c] = H;
}

__global__ __launch_bounds__(256) void scan_pass3(
    const f16x2* __restrict__ a, const f16x2* __restrict__ bv,
    const float2* __restrict__ Hs, f16x2* __restrict__ hb) {
  const int c2 = blockIdx.x * 256 + threadIdx.x;
  const int j = blockIdx.y;
  const int b = blockIdx.z;
  const size_t base = ((size_t)(b * 4096 + j * 32)) * 512 + c2;
  float2 H = Hs[((size_t)(b * 128 + j)) * 512 + c2];
  float h0 = H.x, h1 = H.y;
#pragma unroll 8
  for (int t = 0; t < 32; ++t) {
    const size_t o = base + (size_t)t * 512;
    f16x2 at = a[o], bt = bv[o];
    h0 = (float)at[0] * h0 + (float)bt[0];
    h1 = (float)at[1] * h1 + (float)bt[1];
    f16x2 hv; hv[0] = (f16)h0; hv[1] = (f16)h1;
    hb[o] = hv;
  }
}

extern "C" void kernel_launch(void* const* d_in, const int* in_sizes, int n_in,
                              void* d_out, int out_size, void* d_ws,
                              size_t ws_size, hipStream_t stream) {
  const float* x       = (const float*)d_in[0];
  const float* h_prev  = (const float*)d_in[1];
  const float* gate_w  = (const float*)d_in[2];
  const float* gate_b  = (const float*)d_in[3];
  const float* value_w = (const float*)d_in[4];
  const float* out_w   = (const float*)d_in[5];
  float* out = (float*)d_out;

  char* ws = (char*)d_ws;
  // ws layout (bytes), total ~115.3 MB:
  f16*   xh   = (f16*)(ws);                    // 33,554,432  x f16; reused as h
  f16*   wgv  = (f16*)(ws + 33554432);         //  6,291,456  packed weights
  f16*   owb  = (f16*)(ws + 39845888);         //  2,097,152  out_w f16
  f16*   abuf = (f16*)(ws + 41943040);         // 33,554,432  forget gate a
  f16*   bvb  = (f16*)(ws + 75497472);         // 33,554,432  bv = bg*v
  float* Ac   = (float*)(ws + 109051904);      //  2,097,152
  float* Uc   = (float*)(ws + 111149056);      //  2,097,152
  float* Hs   = (float*)(ws + 113246208);      //  2,097,152
  float* hlast = out + 16777216;

  // fused cast + weight packing
  cast_pack<<<10240, 256, 0, stream>>>(x, gate_w, value_w, out_w, xh, wgv,
                                       owb);

  // gates+values GEMM, fused sigmoid + bv epilogue
  gemm_bt<0><<<dim3(24, 128), 256, 0, stream>>>(xh, wgv, gate_b, abuf, bvb);

  // chunked scan (128 chunks x 32)
  scan_pass1<<<dim3(2, 128, 4), 256, 0, stream>>>(
      (const f16x2*)abuf, (const f16x2*)bvb, (float2*)Ac, (float2*)Uc);
  scan_pass2<<<64, 256, 0, stream>>>(Ac, Uc, h_prev, Hs, hlast);
  scan_pass3<<<dim3(2, 128, 4), 256, 0, stream>>>(
      (const f16x2*)abuf, (const f16x2*)bvb, (const float2*)Hs, (f16x2*)xh);

  // output GEMM -> y fp32
  gemm_bt<1><<<dim3(8, 128), 256, 0, stream>>>(xh, owb, nullptr, out, nullptr);
}